// Round 9
// baseline (3508.945 us; speedup 1.0000x reference)
//
#include <hip/hip_runtime.h>

// RNN: B=32, T=2048, E=256, H=256, L=2, f32.
// Pipelined megakernel (round-8 structure, round-9 dot core):
//   pre: proj0 = x @ W0x + b0 -> ws.A  (grid 256)
//   mega (128 blocks, all co-resident):
//     blk 0-31   L0 scan -> d_out rows; publish flagL0[b] every 64 steps
//     blk 32-95  chasers (2/batch): xproj1 = h0 @ W1x + b1 -> ws.A (in-place
//                overwrite of consumed xproj0 rows); release chunkdone
//     blk 96-127 L1 scan: wait chunkdone; -> d_out rows + final ht
//
// Dot core v9 (1024 thr): lane = qt*16+jl (qt=lane>>4 i-quarter, quad p=lane&3
// = 4 consecutive cols), j = wv*16+jl. Lane holds only 64 weights
// W[64qt+i][j] -> fits the 128-VGPR/wave budget at 4 waves/EU, so no AGPR
// parking (rounds 4-8: 128-elem w[] parked in AGPRs, +1 v_accvgpr_read per
// FMA). Per step: 4 ds_read_b128 (quarter-stride-72 LDS: 16 distinct addrs,
// 2-way bank alias = free), 64 v_fmac_f32_dpp (quad_perm broadcast folded),
// reduce = shfl_xor(16) + shfl_xor(32) (both in-wave). Writers = qt==0 lanes.
// Scan barriers are LDS-only (s_waitcnt lgkmcnt(0); s_barrier) so global
// xp-loads / h-stores stay in flight; global I/O batched in XPB=4 groups.

#define TT 2048
#define BB 32
#define XPB 4
#define QS 72        // quarter stride in floats (64 + 8 pad)
#define CHUNK 64
#define NCHUNK (TT / CHUNK)  // 32

#define FMAC1(acc, hv, wv, QPS)                                               \
    asm("v_fmac_f32_dpp %0, %1, %2 quad_perm:[" QPS "] row_mask:0xf "         \
        "bank_mask:0xf"                                                       \
        : "+v"(acc)                                                           \
        : "v"(hv), "v"(wv))

#define QBLK(S, QPS)                          \
    FMAC1(a0, v.x, w[base + 4 * S + 0], QPS); \
    FMAC1(a1, v.y, w[base + 4 * S + 1], QPS); \
    FMAC1(a2, v.z, w[base + 4 * S + 2], QPS); \
    FMAC1(a3, v.w, w[base + 4 * S + 3], QPS);

// 64-i dot for this lane's quarter + full 4-quarter reduce (all in-wave).
// hb must point at &buf[qt*QS]; leaves total in s (valid in all lanes).
#define DOT64()                                                         \
    float a0 = 0.f, a1 = 0.f, a2 = 0.f, a3 = 0.f;                       \
    _Pragma("unroll")                                                   \
    for (int k = 0; k < 4; ++k) {                                       \
        const int base = 16 * k;                                        \
        float4 v = *reinterpret_cast<const float4*>(hb + base + 4 * p); \
        QBLK(0, "0,0,0,0")                                              \
        QBLK(1, "1,1,1,1")                                              \
        QBLK(2, "2,2,2,2")                                              \
        QBLK(3, "3,3,3,3")                                              \
    }                                                                   \
    float s = (a0 + a1) + (a2 + a3);                                    \
    s += __shfl_xor(s, 16, 64);                                         \
    s += __shfl_xor(s, 32, 64);

#define LDS_BARRIER() asm volatile("s_waitcnt lgkmcnt(0)\n\ts_barrier" ::: "memory")

// LDS position of h element i (i in [0,256)) in quarter-strided layout
__device__ __forceinline__ int hpos(int i) { return QS * (i >> 6) + (i & 63); }

__device__ __forceinline__ int aload(int* pf) {
    return __hip_atomic_load(pf, __ATOMIC_ACQUIRE, __HIP_MEMORY_SCOPE_AGENT);
}
__device__ __forceinline__ void astore(int* pf, int v) {
    __hip_atomic_store(pf, v, __ATOMIC_RELEASE, __HIP_MEMORY_SCOPE_AGENT);
}

__global__ __launch_bounds__(1024, 4) void proj9_kernel(
    const float* in, const float* __restrict__ W, const float* __restrict__ bias,
    float* out, int rows_per_wg)
{
    __shared__ float rb[2][4 * QS];
    const int tid = threadIdx.x;
    const int lane = tid & 63;
    const int wv = tid >> 6;
    const int p = lane & 3;
    const int qt = lane >> 4;
    const int j = wv * 16 + (lane & 15);
    const bool wr = (qt == 0);

    float w[64];
#pragma unroll
    for (int i = 0; i < 64; ++i)
        w[i] = W[(size_t)(qt * 64 + i) * 256 + j];
    const float bj = bias[j];

    const size_t r0 = (size_t)blockIdx.x * rows_per_wg;
    if (tid < 64) {
        float4 t4 = reinterpret_cast<const float4*>(in + r0 * 256)[tid];
        *reinterpret_cast<float4*>(&rb[0][hpos(4 * tid)]) = t4;
    }
    __syncthreads();

    for (int rr = 0; rr < rows_per_wg; ++rr) {
        const int buf = rr & 1;
        if (rr + 1 < rows_per_wg && tid < 64) {
            float4 t4 = reinterpret_cast<const float4*>(in + (r0 + rr + 1) * 256)[tid];
            *reinterpret_cast<float4*>(&rb[buf ^ 1][hpos(4 * tid)]) = t4;
        }
        const float* hb = &rb[buf][qt * QS];
        DOT64()
        if (wr) out[(r0 + rr) * 256 + j] = s + bj;
        // full barrier (vmcnt drain): safe for the in-place fallback path
        __syncthreads();
    }
}

// serial fallback scan
__global__ __launch_bounds__(1024, 4) void scan9_kernel(
    const float* __restrict__ W, const float* __restrict__ h_init,
    float* __restrict__ io, float* __restrict__ hfinal)
{
    __shared__ float hbuf[2][4 * QS];
    const int tid = threadIdx.x;
    const int lane = tid & 63;
    const int wv = tid >> 6;
    const int p = lane & 3;
    const int qt = lane >> 4;
    const int j = wv * 16 + (lane & 15);
    const int b = blockIdx.x;
    const bool wr = (qt == 0);

    float w[64];
#pragma unroll
    for (int i = 0; i < 64; ++i)
        w[i] = W[(size_t)(256 + qt * 64 + i) * 256 + j];

    if (tid < 256) hbuf[0][hpos(tid)] = h_init[b * 256 + tid];

    float* iob = io + (size_t)b * TT * 256;
    float xpc[XPB], xpn[XPB], hs[XPB];
    if (wr) {
#pragma unroll
        for (int u = 0; u < XPB; ++u) xpc[u] = iob[(size_t)u * 256 + j];
    }
    __syncthreads();

    for (int t0 = 0; t0 < TT; t0 += XPB) {
        const bool more = (t0 + XPB) < TT;
        if (wr && more) {
#pragma unroll
            for (int u = 0; u < XPB; ++u)
                xpn[u] = iob[(size_t)(t0 + XPB + u) * 256 + j];
        }
#pragma unroll
        for (int u = 0; u < XPB; ++u) {
            const int t = t0 + u;
            const float* hb = &hbuf[t & 1][qt * QS];
            DOT64()
            if (wr) {
                const float z = s + xpc[u];
                const float e = __expf(2.0f * z);
                const float hn = 1.0f - 2.0f / (e + 1.0f);
                hbuf[(t + 1) & 1][hpos(j)] = hn;
                hs[u] = hn;
            }
            LDS_BARRIER();
        }
        if (wr) {
#pragma unroll
            for (int u = 0; u < XPB; ++u)
                iob[(size_t)(t0 + u) * 256 + j] = hs[u];
            if (hfinal != nullptr && t0 == TT - XPB)
                hfinal[b * 256 + j] = hs[XPB - 1];
        }
        if (more) {
#pragma unroll
            for (int u = 0; u < XPB; ++u) xpc[u] = xpn[u];
        }
    }
}

__global__ __launch_bounds__(1024, 4) void mega9_kernel(
    const float* __restrict__ W0, const float* __restrict__ W1,
    const float* __restrict__ b1v, const float* __restrict__ h0init,
    float* xpA, float* out, int* flags)
{
    __shared__ float lds[2][4 * QS];
    const int tid = threadIdx.x;
    const int lane = tid & 63;
    const int wv = tid >> 6;
    const int p = lane & 3;
    const int qt = lane >> 4;
    const int j = wv * 16 + (lane & 15);
    const bool wr = (qt == 0);
    const int bid = blockIdx.x;
    int* flagL0 = flags;
    int* chunkdone = flags + BB;

    if (bid < BB || bid >= 3 * BB) {
        // ---- scan roles ----
        const bool isL0 = (bid < BB);
        const int b = isL0 ? bid : bid - 3 * BB;
        const float* W = isL0 ? W0 : W1;
        const float* h_init = isL0 ? h0init : (h0init + BB * 256);

        float w[64];
#pragma unroll
        for (int i = 0; i < 64; ++i)
            w[i] = W[(size_t)(256 + qt * 64 + i) * 256 + j];

        if (tid < 256) lds[0][hpos(tid)] = h_init[b * 256 + tid];

        const float* xsrc = xpA + (size_t)b * TT * 256;
        float* hdst = out + (size_t)b * TT * 256;
        float xpc[XPB], xpn[XPB], hs[XPB];

        if (isL0) {
            if (wr) {
#pragma unroll
                for (int u = 0; u < XPB; ++u) xpc[u] = xsrc[(size_t)u * 256 + j];
            }
            __syncthreads();
            for (int t0 = 0; t0 < TT; t0 += XPB) {
                const bool more = (t0 + XPB) < TT;
                if (wr && more) {
#pragma unroll
                    for (int u = 0; u < XPB; ++u)
                        xpn[u] = xsrc[(size_t)(t0 + XPB + u) * 256 + j];
                }
#pragma unroll
                for (int u = 0; u < XPB; ++u) {
                    const int t = t0 + u;
                    const float* hb = &lds[t & 1][qt * QS];
                    DOT64()
                    if (wr) {
                        const float z = s + xpc[u];
                        const float e = __expf(2.0f * z);
                        const float hn = 1.0f - 2.0f / (e + 1.0f);
                        lds[(t + 1) & 1][hpos(j)] = hn;
                        hs[u] = hn;
                    }
                    LDS_BARRIER();
                }
                if (wr) {
#pragma unroll
                    for (int u = 0; u < XPB; ++u)
                        hdst[(size_t)(t0 + u) * 256 + j] = hs[u];
                }
                if (((t0 + XPB) & (CHUNK - 1)) == 0) {
                    __threadfence();
                    __syncthreads();
                    if (tid == 0) astore(&flagL0[b], t0 + XPB);
                }
                if (more) {
#pragma unroll
                    for (int u = 0; u < XPB; ++u) xpc[u] = xpn[u];
                }
            }
        } else {
            __syncthreads();
            for (int chunk = 0; chunk < NCHUNK; ++chunk) {
                const int tbase = chunk * CHUNK;
                while (aload(&chunkdone[b * NCHUNK + chunk]) == 0)
                    __builtin_amdgcn_s_sleep(1);
                if (wr) {
#pragma unroll
                    for (int u = 0; u < XPB; ++u)
                        xpc[u] = xsrc[(size_t)(tbase + u) * 256 + j];
                }
                for (int g = 0; g < CHUNK / XPB; ++g) {
                    const int t0 = tbase + g * XPB;
                    if (wr && g + 1 < CHUNK / XPB) {
#pragma unroll
                        for (int u = 0; u < XPB; ++u)
                            xpn[u] = xsrc[(size_t)(t0 + XPB + u) * 256 + j];
                    }
#pragma unroll
                    for (int u = 0; u < XPB; ++u) {
                        const int t = t0 + u;
                        const float* hb = &lds[t & 1][qt * QS];
                        DOT64()
                        if (wr) {
                            const float z = s + xpc[u];
                            const float e = __expf(2.0f * z);
                            const float hn = 1.0f - 2.0f / (e + 1.0f);
                            lds[(t + 1) & 1][hpos(j)] = hn;
                            hs[u] = hn;
                        }
                        LDS_BARRIER();
                    }
                    if (wr) {
#pragma unroll
                        for (int u = 0; u < XPB; ++u)
                            hdst[(size_t)(t0 + u) * 256 + j] = hs[u];
                        if (t0 + XPB == TT)
                            out[(size_t)BB * TT * 256 + b * 256 + j] = hs[XPB - 1];
                    }
                    if (g + 1 < CHUNK / XPB) {
#pragma unroll
                        for (int u = 0; u < XPB; ++u) xpc[u] = xpn[u];
                    }
                }
            }
        }
    } else {
        // ---- proj1 chasers ----
        const int k = bid - BB;  // 0..63
        const int b = k >> 1;
        const int half = k & 1;

        float w[64];
#pragma unroll
        for (int i = 0; i < 64; ++i)
            w[i] = W1[(size_t)(qt * 64 + i) * 256 + j];
        const float bj = b1v[j];

        for (int chunk = half; chunk < NCHUNK; chunk += 2) {
            while (aload(&flagL0[b]) < (chunk + 1) * CHUNK)
                __builtin_amdgcn_s_sleep(1);
            const int tbase = chunk * CHUNK;
            const float* src = out + ((size_t)b * TT + tbase) * 256;  // h0 rows
            float* dst = xpA + ((size_t)b * TT + tbase) * 256;        // xproj1

            if (tid < 64) {
                float4 t4 = reinterpret_cast<const float4*>(src)[tid];
                *reinterpret_cast<float4*>(&lds[0][hpos(4 * tid)]) = t4;
            }
            __syncthreads();
            for (int r = 0; r < CHUNK; ++r) {
                const int buf = r & 1;
                if (r + 1 < CHUNK && tid < 64) {
                    float4 t4 =
                        reinterpret_cast<const float4*>(src + (size_t)(r + 1) * 256)[tid];
                    *reinterpret_cast<float4*>(&lds[buf ^ 1][hpos(4 * tid)]) = t4;
                }
                const float* hb = &lds[buf][qt * QS];
                DOT64()
                if (wr) dst[(size_t)r * 256 + j] = s + bj;
                __syncthreads();
            }
            __threadfence();
            __syncthreads();
            if (tid == 0) astore(&chunkdone[b * NCHUNK + chunk], 1);
        }
    }
}

extern "C" void kernel_launch(void* const* d_in, const int* in_sizes, int n_in,
                              void* d_out, int out_size, void* d_ws, size_t ws_size,
                              hipStream_t stream) {
    const float* x  = (const float*)d_in[0];  // [B,T,256]
    const float* h0 = (const float*)d_in[1];  // [2,B,256]
    const float* W0 = (const float*)d_in[2];  // [512,256]
    const float* b0 = (const float*)d_in[3];  // [256]
    const float* W1 = (const float*)d_in[4];  // [512,256]
    const float* b1 = (const float*)d_in[5];  // [256]
    float* out = (float*)d_out;               // [B*T*256] + [B*256]

    const size_t XPA_FLOATS = (size_t)BB * TT * 256;  // 64 MB
    const size_t FLAG_BYTES = (size_t)(BB + BB * NCHUNK) * sizeof(int);
    const size_t NEEDED = XPA_FLOATS * 4 + FLAG_BYTES;

    if (ws_size >= NEEDED) {
        float* xpA = (float*)d_ws;
        int* flags = (int*)((char*)d_ws + XPA_FLOATS * 4);
        hipMemsetAsync(flags, 0, FLAG_BYTES, stream);
        proj9_kernel<<<256, 1024, 0, stream>>>(x, W0, b0, xpA, 256);
        mega9_kernel<<<4 * BB, 1024, 0, stream>>>(W0, W1, b1, h0, xpA, out, flags);
    } else {
        proj9_kernel<<<256, 1024, 0, stream>>>(x, W0, b0, out, 256);
        scan9_kernel<<<BB, 1024, 0, stream>>>(W0, h0, out, nullptr);
        proj9_kernel<<<256, 1024, 0, stream>>>(out, W1, b1, out, 256);
        scan9_kernel<<<BB, 1024, 0, stream>>>(W1, h0 + BB * 256, out, out + XPA_FLOATS);
    }
}

// Round 10
// 2945.294 us; speedup vs baseline: 1.1914x; 1.1914x over previous
//
#include <hip/hip_runtime.h>

// RNN: B=32, T=2048, E=256, H=256, L=2, f32.
// Pipelined megakernel (round-8 structure + grouped-asm dot core):
//   pre: proj0 = x @ W0x + b0 -> ws.A  (grid 256)
//   mega (192 blocks, all co-resident at 1 block/CU):
//     blk 0-31    L0 scan -> d_out rows; publish flagL0[b] every 64 steps
//     blk 32-159  chasers (4/batch): xproj1 = h0 @ W1x + b1 -> ws.A (in-place
//                 overwrite of consumed xproj0 rows); release chunkdone
//     blk 160-191 L1 scan: wait chunkdone; -> d_out rows + final ht
//
// Dot core: 512 thr, p=tid&3, q=tid>>2, c=q&1 (i-half), j=(q>>1)*4+p. Lane
// holds 128 weights W[128c+i][j]. Per 16-wide i-block: one ds_read_b128
// (compiler-emitted, HPAD=144 layout = conflict-free), then ONE asm with 16
// v_fmac_f32_dpp and 24 operands (4 accs, 4 h floats, 16 weights). Grouping
// 16 weights per asm forces 16 simultaneous VGPR materializations per use
// site, making AGPR-parking strictly unprofitable (rounds 4-9: per-FMA asm
// let the allocator park w[] in AGPRs, +1 v_accvgpr_read per FMA; VGPR_Count
// 84/96/60 < weight count each time).
// Scan barriers: "s_waitcnt lgkmcnt(0); s_barrier" (LDS-only visibility;
// lane-private global xp-loads/h-stores stay in flight). XPB=8 batching.
// Flags padded to 64B cachelines (r8 had 96 CUs polling one line).

#define TT 2048
#define BB 32
#define XPB 8
#define HPAD 144  // padded stride of one 128-float h half
#define CHUNK 64
#define NCHUNK (TT / CHUNK)  // 32

#define RM " row_mask:0xf bank_mask:0xf\n\t"

// one 16-FMA group: accs a0..a3; v = h float4 (quad-shared via DPP); 16 w.
#define DOTG(vv, ww, base)                                              \
    asm("v_fmac_f32_dpp %0, %4, %8  quad_perm:[0,0,0,0]" RM             \
        "v_fmac_f32_dpp %1, %5, %9  quad_perm:[0,0,0,0]" RM             \
        "v_fmac_f32_dpp %2, %6, %10 quad_perm:[0,0,0,0]" RM             \
        "v_fmac_f32_dpp %3, %7, %11 quad_perm:[0,0,0,0]" RM             \
        "v_fmac_f32_dpp %0, %4, %12 quad_perm:[1,1,1,1]" RM             \
        "v_fmac_f32_dpp %1, %5, %13 quad_perm:[1,1,1,1]" RM             \
        "v_fmac_f32_dpp %2, %6, %14 quad_perm:[1,1,1,1]" RM             \
        "v_fmac_f32_dpp %3, %7, %15 quad_perm:[1,1,1,1]" RM             \
        "v_fmac_f32_dpp %0, %4, %16 quad_perm:[2,2,2,2]" RM             \
        "v_fmac_f32_dpp %1, %5, %17 quad_perm:[2,2,2,2]" RM             \
        "v_fmac_f32_dpp %2, %6, %18 quad_perm:[2,2,2,2]" RM             \
        "v_fmac_f32_dpp %3, %7, %19 quad_perm:[2,2,2,2]" RM             \
        "v_fmac_f32_dpp %0, %4, %20 quad_perm:[3,3,3,3]" RM             \
        "v_fmac_f32_dpp %1, %5, %21 quad_perm:[3,3,3,3]" RM             \
        "v_fmac_f32_dpp %2, %6, %22 quad_perm:[3,3,3,3]" RM             \
        "v_fmac_f32_dpp %3, %7, %23 quad_perm:[3,3,3,3]" RM             \
        : "+v"(a0), "+v"(a1), "+v"(a2), "+v"(a3)                        \
        : "v"((vv).x), "v"((vv).y), "v"((vv).z), "v"((vv).w),           \
          "v"((ww)[(base) + 0]), "v"((ww)[(base) + 1]),                 \
          "v"((ww)[(base) + 2]), "v"((ww)[(base) + 3]),                 \
          "v"((ww)[(base) + 4]), "v"((ww)[(base) + 5]),                 \
          "v"((ww)[(base) + 6]), "v"((ww)[(base) + 7]),                 \
          "v"((ww)[(base) + 8]), "v"((ww)[(base) + 9]),                 \
          "v"((ww)[(base) + 10]), "v"((ww)[(base) + 11]),               \
          "v"((ww)[(base) + 12]), "v"((ww)[(base) + 13]),               \
          "v"((ww)[(base) + 14]), "v"((ww)[(base) + 15]))

// full 128-dot + cross-half reduce; leaves total in s (valid in all lanes)
#define DOT128()                                                          \
    float a0 = 0.f, a1 = 0.f, a2 = 0.f, a3 = 0.f;                         \
    _Pragma("unroll")                                                     \
    for (int k = 0; k < 8; ++k) {                                         \
        float4 v = *reinterpret_cast<const float4*>(hb + 16 * k + 4 * p); \
        DOTG(v, w, 16 * k);                                               \
    }                                                                     \
    float s = (a0 + a1) + (a2 + a3);                                      \
    s += __shfl_xor(s, 4, 64);

#define LDS_BARRIER() asm volatile("s_waitcnt lgkmcnt(0)\n\ts_barrier" ::: "memory")

// padded LDS index for h element i (i in [0,256))
__device__ __forceinline__ int hidx(int i) { return HPAD * (i >> 7) + (i & 127); }

__device__ __forceinline__ int aload(int* pf) {
    return __hip_atomic_load(pf, __ATOMIC_ACQUIRE, __HIP_MEMORY_SCOPE_AGENT);
}
__device__ __forceinline__ void astore(int* pf, int v) {
    __hip_atomic_store(pf, v, __ATOMIC_RELEASE, __HIP_MEMORY_SCOPE_AGENT);
}

__global__ __launch_bounds__(512)
__attribute__((amdgpu_waves_per_eu(2, 2))) void proj10_kernel(
    const float* in, const float* __restrict__ W, const float* __restrict__ bias,
    float* out, int rows_per_wg)
{
    __shared__ float rb[2][2 * HPAD];
    const int tid = threadIdx.x;
    const int p = tid & 3;
    const int q = tid >> 2;
    const int c = q & 1;
    const int j = (q >> 1) * 4 + p;

    float w[128];
#pragma unroll
    for (int i = 0; i < 128; ++i)
        w[i] = W[(size_t)(c * 128 + i) * 256 + j];
    const float bj = bias[j];

    const size_t r0 = (size_t)blockIdx.x * rows_per_wg;
    if (tid < 64) {
        float4 t4 = reinterpret_cast<const float4*>(in + r0 * 256)[tid];
        *reinterpret_cast<float4*>(&rb[0][hidx(4 * tid)]) = t4;
    }
    __syncthreads();

    for (int rr = 0; rr < rows_per_wg; ++rr) {
        const int buf = rr & 1;
        if (rr + 1 < rows_per_wg && tid < 64) {
            float4 t4 = reinterpret_cast<const float4*>(in + (r0 + rr + 1) * 256)[tid];
            *reinterpret_cast<float4*>(&rb[buf ^ 1][hidx(4 * tid)]) = t4;
        }
        const float* hb = &rb[buf][HPAD * c];
        DOT128()
        if (c == 0) out[(r0 + rr) * 256 + j] = s + bj;
        // full barrier (vmcnt drain): required for in==out aliasing (fallback)
        __syncthreads();
    }
}

// serial fallback scan
__global__ __launch_bounds__(512)
__attribute__((amdgpu_waves_per_eu(2, 2))) void scan10_kernel(
    const float* __restrict__ W, const float* __restrict__ h_init,
    float* __restrict__ io, float* __restrict__ hfinal)
{
    __shared__ float hbuf[2][2 * HPAD];
    const int tid = threadIdx.x;
    const int p = tid & 3;
    const int q = tid >> 2;
    const int c = q & 1;
    const int j = (q >> 1) * 4 + p;
    const int b = blockIdx.x;
    const bool wr = (c == 0);

    float w[128];
#pragma unroll
    for (int i = 0; i < 128; ++i)
        w[i] = W[(size_t)(256 + c * 128 + i) * 256 + j];

    if (tid < 256) hbuf[0][hidx(tid)] = h_init[b * 256 + tid];

    float* iob = io + (size_t)b * TT * 256;
    float xpc[XPB], xpn[XPB], hs[XPB];
    if (wr) {
#pragma unroll
        for (int u = 0; u < XPB; ++u) xpc[u] = iob[(size_t)u * 256 + j];
    }
    __syncthreads();

    for (int t0 = 0; t0 < TT; t0 += XPB) {
        const bool more = (t0 + XPB) < TT;
        if (wr && more) {
#pragma unroll
            for (int u = 0; u < XPB; ++u)
                xpn[u] = iob[(size_t)(t0 + XPB + u) * 256 + j];
        }
#pragma unroll
        for (int u = 0; u < XPB; ++u) {
            const int t = t0 + u;
            const float* hb = &hbuf[t & 1][HPAD * c];
            DOT128()
            if (wr) {
                const float z = s + xpc[u];
                const float e = __expf(2.0f * z);
                const float hn = 1.0f - 2.0f / (e + 1.0f);
                hbuf[(t + 1) & 1][hidx(j)] = hn;
                hs[u] = hn;
            }
            LDS_BARRIER();
        }
        if (wr) {
#pragma unroll
            for (int u = 0; u < XPB; ++u)
                iob[(size_t)(t0 + u) * 256 + j] = hs[u];
            if (hfinal != nullptr && t0 == TT - XPB)
                hfinal[b * 256 + j] = hs[XPB - 1];
        }
        if (more) {
#pragma unroll
            for (int u = 0; u < XPB; ++u) xpc[u] = xpn[u];
        }
    }
}

__global__ __launch_bounds__(512)
__attribute__((amdgpu_waves_per_eu(2, 2))) void mega10_kernel(
    const float* __restrict__ W0, const float* __restrict__ W1,
    const float* __restrict__ b1v, const float* __restrict__ h0init,
    float* xpA, float* out, int* flags)
{
    __shared__ float lds[2][2 * HPAD];
    const int tid = threadIdx.x;
    const int p = tid & 3;
    const int q = tid >> 2;
    const int c = q & 1;
    const int j = (q >> 1) * 4 + p;
    const bool wr = (c == 0);
    const int bid = blockIdx.x;
    int* flagL0 = flags;             // stride 16 ints per batch (64B)
    int* chunkdone = flags + BB * 16;  // stride 64 ints per batch

    if (bid < BB || bid >= 5 * BB) {
        // ---- scan roles ----
        const bool isL0 = (bid < BB);
        const int b = isL0 ? bid : bid - 5 * BB;
        const float* W = isL0 ? W0 : W1;
        const float* h_init = isL0 ? h0init : (h0init + BB * 256);

        float w[128];
#pragma unroll
        for (int i = 0; i < 128; ++i)
            w[i] = W[(size_t)(256 + c * 128 + i) * 256 + j];

        if (tid < 256) lds[0][hidx(tid)] = h_init[b * 256 + tid];

        const float* xsrc = xpA + (size_t)b * TT * 256;
        float* hdst = out + (size_t)b * TT * 256;
        float xpc[XPB], xpn[XPB], hs[XPB];

        if (isL0) {
            if (wr) {
#pragma unroll
                for (int u = 0; u < XPB; ++u) xpc[u] = xsrc[(size_t)u * 256 + j];
            }
            __syncthreads();
            for (int t0 = 0; t0 < TT; t0 += XPB) {
                const bool more = (t0 + XPB) < TT;
                if (wr && more) {
#pragma unroll
                    for (int u = 0; u < XPB; ++u)
                        xpn[u] = xsrc[(size_t)(t0 + XPB + u) * 256 + j];
                }
#pragma unroll
                for (int u = 0; u < XPB; ++u) {
                    const int t = t0 + u;
                    const float* hb = &lds[t & 1][HPAD * c];
                    DOT128()
                    if (wr) {
                        const float z = s + xpc[u];
                        const float e = __expf(2.0f * z);
                        const float hn = 1.0f - 2.0f / (e + 1.0f);
                        lds[(t + 1) & 1][hidx(j)] = hn;
                        hs[u] = hn;
                    }
                    LDS_BARRIER();
                }
                if (wr) {
#pragma unroll
                    for (int u = 0; u < XPB; ++u)
                        hdst[(size_t)(t0 + u) * 256 + j] = hs[u];
                }
                if (((t0 + XPB) & (CHUNK - 1)) == 0) {
                    __threadfence();
                    __syncthreads();
                    if (tid == 0) astore(&flagL0[b * 16], t0 + XPB);
                }
                if (more) {
#pragma unroll
                    for (int u = 0; u < XPB; ++u) xpc[u] = xpn[u];
                }
            }
        } else {
            __syncthreads();
            for (int chunk = 0; chunk < NCHUNK; ++chunk) {
                const int tbase = chunk * CHUNK;
                while (aload(&chunkdone[b * 64 + chunk]) == 0)
                    __builtin_amdgcn_s_sleep(1);
                if (wr) {
#pragma unroll
                    for (int u = 0; u < XPB; ++u)
                        xpc[u] = xsrc[(size_t)(tbase + u) * 256 + j];
                }
                for (int g = 0; g < CHUNK / XPB; ++g) {
                    const int t0 = tbase + g * XPB;
                    if (wr && g + 1 < CHUNK / XPB) {
#pragma unroll
                        for (int u = 0; u < XPB; ++u)
                            xpn[u] = xsrc[(size_t)(t0 + XPB + u) * 256 + j];
                    }
#pragma unroll
                    for (int u = 0; u < XPB; ++u) {
                        const int t = t0 + u;
                        const float* hb = &lds[t & 1][HPAD * c];
                        DOT128()
                        if (wr) {
                            const float z = s + xpc[u];
                            const float e = __expf(2.0f * z);
                            const float hn = 1.0f - 2.0f / (e + 1.0f);
                            lds[(t + 1) & 1][hidx(j)] = hn;
                            hs[u] = hn;
                        }
                        LDS_BARRIER();
                    }
                    if (wr) {
#pragma unroll
                        for (int u = 0; u < XPB; ++u)
                            hdst[(size_t)(t0 + u) * 256 + j] = hs[u];
                        if (t0 + XPB == TT)
                            out[(size_t)BB * TT * 256 + b * 256 + j] = hs[XPB - 1];
                    }
                    if (g + 1 < CHUNK / XPB) {
#pragma unroll
                        for (int u = 0; u < XPB; ++u) xpc[u] = xpn[u];
                    }
                }
            }
        }
    } else {
        // ---- proj1 chasers (4 per batch) ----
        const int k = bid - BB;  // 0..127
        const int b = k >> 2;
        const int quarter = k & 3;

        float w[128];
#pragma unroll
        for (int i = 0; i < 128; ++i)
            w[i] = W1[(size_t)(c * 128 + i) * 256 + j];
        const float bj = b1v[j];

        for (int chunk = quarter; chunk < NCHUNK; chunk += 4) {
            while (aload(&flagL0[b * 16]) < (chunk + 1) * CHUNK)
                __builtin_amdgcn_s_sleep(1);
            const int tbase = chunk * CHUNK;
            const float* src = out + ((size_t)b * TT + tbase) * 256;  // h0 rows
            float* dst = xpA + ((size_t)b * TT + tbase) * 256;        // xproj1

            if (tid < 64) {
                float4 t4 = reinterpret_cast<const float4*>(src)[tid];
                *reinterpret_cast<float4*>(&lds[0][hidx(4 * tid)]) = t4;
            }
            __syncthreads();
            for (int r = 0; r < CHUNK; ++r) {
                const int buf = r & 1;
                if (r + 1 < CHUNK && tid < 64) {
                    float4 t4 =
                        reinterpret_cast<const float4*>(src + (size_t)(r + 1) * 256)[tid];
                    *reinterpret_cast<float4*>(&lds[buf ^ 1][hidx(4 * tid)]) = t4;
                }
                const float* hb = &lds[buf][HPAD * c];
                DOT128()
                if (wr) dst[(size_t)r * 256 + j] = s + bj;
                __syncthreads();
            }
            __threadfence();
            __syncthreads();
            if (tid == 0) astore(&chunkdone[b * 64 + chunk], 1);
        }
    }
}

extern "C" void kernel_launch(void* const* d_in, const int* in_sizes, int n_in,
                              void* d_out, int out_size, void* d_ws, size_t ws_size,
                              hipStream_t stream) {
    const float* x  = (const float*)d_in[0];  // [B,T,256]
    const float* h0 = (const float*)d_in[1];  // [2,B,256]
    const float* W0 = (const float*)d_in[2];  // [512,256]
    const float* b0 = (const float*)d_in[3];  // [256]
    const float* W1 = (const float*)d_in[4];  // [512,256]
    const float* b1 = (const float*)d_in[5];  // [256]
    float* out = (float*)d_out;               // [B*T*256] + [B*256]

    const size_t XPA_FLOATS = (size_t)BB * TT * 256;  // 64 MB
    const size_t FLAG_INTS = (size_t)BB * 16 + (size_t)BB * 64;  // padded flags
    const size_t NEEDED = XPA_FLOATS * 4 + FLAG_INTS * 4;

    if (ws_size >= NEEDED) {
        float* xpA = (float*)d_ws;
        int* flags = (int*)((char*)d_ws + XPA_FLOATS * 4);
        hipMemsetAsync(flags, 0, FLAG_INTS * 4, stream);
        proj10_kernel<<<256, 512, 0, stream>>>(x, W0, b0, xpA, 256);
        mega10_kernel<<<6 * BB, 512, 0, stream>>>(W0, W1, b1, h0, xpA, out, flags);
    } else {
        proj10_kernel<<<256, 512, 0, stream>>>(x, W0, b0, out, 256);
        scan10_kernel<<<BB, 512, 0, stream>>>(W0, h0, out, nullptr);
        proj10_kernel<<<256, 512, 0, stream>>>(out, W1, b1, out, 256);
        scan10_kernel<<<BB, 512, 0, stream>>>(W1, h0 + BB * 256, out, out + XPA_FLOATS);
    }
}

// Round 12
// 2676.533 us; speedup vs baseline: 1.3110x; 1.1004x over previous
//
#include <hip/hip_runtime.h>

// RNN: B=32, T=2048, E=256, H=256, L=2, f32.
// Pipelined megakernel (r8-proven structure + relaxed-poll fix):
//   pre: proj0 = x @ W0x + b0 -> ws.A  (grid 256)
//   mega (128 blocks, all co-resident):
//     blk 0-31   L0 scan -> d_out rows; publish flagL0[b] every CHUNK steps
//     blk 32-95  chasers (2/batch): xproj1 = h0 @ W1x + b1 -> ws.A (in-place
//                overwrite of consumed xproj0 rows); release chunkdone
//     blk 96-127 L1 scan: wait chunkdone -> d_out rows (overwrite h0) + ht
//
// SYNC FIX (r12): consumers poll with RELAXED agent atomic loads (acquire-
// per-poll emitted an L2 invalidate EVERY iteration -> consumer XCD L2 cold
// + same-XCD L0 blocks trashed; r8's L1 ran 1.45x slower than L0). After the
// flag is observed: ONE __threadfence() (wb+inv) gives the acquire ordering.
// CHUNK 64->32 halves the steady-state trail.
//
// Dot core (r4/r6/r8-proven): 512 thr, p=tid&3, q=tid>>2, c=q&1, j=(q>>1)*4+p;
// 128 weights/lane, ds_read_b128 (HPAD=144, conflict-free) + per-FMA
// v_fmac_f32_dpp (quad_perm broadcast folded), shfl_xor(4) reduce. The
// allocator's AGPR-parking tax (+1 v_accvgpr_read per FMA) is accepted —
// 7 attempts to remove it failed (launch_bounds / waves_per_eu / clobber /
// grouped asm / remap / AGPR-direct-VALU=illegal).
// Scan barriers: "s_waitcnt lgkmcnt(0); s_barrier"; global I/O in XPB=8 groups.

#define TT 2048
#define BB 32
#define XPB 8
#define HPAD 144  // padded stride of one 128-float h half
#define CHUNK 32
#define NCHUNK (TT / CHUNK)  // 64

#define FMAC1(acc, hv, wv, QPS)                                               \
    asm("v_fmac_f32_dpp %0, %1, %2 quad_perm:[" QPS "] row_mask:0xf "         \
        "bank_mask:0xf"                                                       \
        : "+v"(acc)                                                           \
        : "v"(hv), "v"(wv))

#define QBLK(S, QPS)                          \
    FMAC1(a0, v.x, w[base + 4 * S + 0], QPS); \
    FMAC1(a1, v.y, w[base + 4 * S + 1], QPS); \
    FMAC1(a2, v.z, w[base + 4 * S + 2], QPS); \
    FMAC1(a3, v.w, w[base + 4 * S + 3], QPS);

#define DOT128()                                                        \
    float a0 = 0.f, a1 = 0.f, a2 = 0.f, a3 = 0.f;                       \
    _Pragma("unroll")                                                   \
    for (int k = 0; k < 8; ++k) {                                       \
        const int base = 16 * k;                                        \
        float4 v = *reinterpret_cast<const float4*>(hb + base + 4 * p); \
        QBLK(0, "0,0,0,0")                                              \
        QBLK(1, "1,1,1,1")                                              \
        QBLK(2, "2,2,2,2")                                              \
        QBLK(3, "3,3,3,3")                                              \
    }                                                                   \
    float s = (a0 + a1) + (a2 + a3);                                    \
    s += __shfl_xor(s, 4, 64);

#define LDS_BARRIER() asm volatile("s_waitcnt lgkmcnt(0)\n\ts_barrier" ::: "memory")

__device__ __forceinline__ int hidx(int i) { return HPAD * (i >> 7) + (i & 127); }

// RELAXED poll load: no per-iteration L2 invalidate.
__device__ __forceinline__ int rload(int* pf) {
    return __hip_atomic_load(pf, __ATOMIC_RELAXED, __HIP_MEMORY_SCOPE_AGENT);
}
__device__ __forceinline__ void astore(int* pf, int v) {
    __hip_atomic_store(pf, v, __ATOMIC_RELEASE, __HIP_MEMORY_SCOPE_AGENT);
}

__global__ __launch_bounds__(512)
__attribute__((amdgpu_waves_per_eu(2, 2))) void proj12_kernel(
    const float* in, const float* __restrict__ W, const float* __restrict__ bias,
    float* out, int rows_per_wg)
{
    __shared__ float rb[2][2 * HPAD];
    const int tid = threadIdx.x;
    const int p = tid & 3;
    const int q = tid >> 2;
    const int c = q & 1;
    const int j = (q >> 1) * 4 + p;

    float w[128];
#pragma unroll
    for (int i = 0; i < 128; ++i)
        w[i] = W[(size_t)(c * 128 + i) * 256 + j];
    const float bj = bias[j];

    const size_t r0 = (size_t)blockIdx.x * rows_per_wg;
    if (tid < 64) {
        float4 t4 = reinterpret_cast<const float4*>(in + r0 * 256)[tid];
        *reinterpret_cast<float4*>(&rb[0][hidx(4 * tid)]) = t4;
    }
    __syncthreads();

    for (int rr = 0; rr < rows_per_wg; ++rr) {
        const int buf = rr & 1;
        if (rr + 1 < rows_per_wg && tid < 64) {
            float4 t4 = reinterpret_cast<const float4*>(in + (r0 + rr + 1) * 256)[tid];
            *reinterpret_cast<float4*>(&rb[buf ^ 1][hidx(4 * tid)]) = t4;
        }
        const float* hb = &rb[buf][HPAD * c];
        DOT128()
        if (c == 0) out[(r0 + rr) * 256 + j] = s + bj;
        // full barrier (vmcnt drain): required for in==out aliasing (fallback)
        __syncthreads();
    }
}

// serial fallback scan (r6-proven)
__global__ __launch_bounds__(512)
__attribute__((amdgpu_waves_per_eu(2, 2))) void scan12_kernel(
    const float* __restrict__ W, const float* __restrict__ h_init,
    float* __restrict__ io, float* __restrict__ hfinal)
{
    __shared__ float hbuf[2][2 * HPAD];
    const int tid = threadIdx.x;
    const int p = tid & 3;
    const int q = tid >> 2;
    const int c = q & 1;
    const int j = (q >> 1) * 4 + p;
    const int b = blockIdx.x;
    const bool wr = (c == 0);

    float w[128];
#pragma unroll
    for (int i = 0; i < 128; ++i)
        w[i] = W[(size_t)(256 + c * 128 + i) * 256 + j];

    if (tid < 256) hbuf[0][hidx(tid)] = h_init[b * 256 + tid];

    float* iob = io + (size_t)b * TT * 256;
    float xpc[XPB], xpn[XPB], hs[XPB];
    if (wr) {
#pragma unroll
        for (int u = 0; u < XPB; ++u) xpc[u] = iob[(size_t)u * 256 + j];
    }
    __syncthreads();

    for (int t0 = 0; t0 < TT; t0 += XPB) {
        const bool more = (t0 + XPB) < TT;
        if (wr && more) {
#pragma unroll
            for (int u = 0; u < XPB; ++u)
                xpn[u] = iob[(size_t)(t0 + XPB + u) * 256 + j];
        }
#pragma unroll
        for (int u = 0; u < XPB; ++u) {
            const int t = t0 + u;
            const float* hb = &hbuf[t & 1][HPAD * c];
            DOT128()
            if (wr) {
                const float z = s + xpc[u];
                const float e = __expf(2.0f * z);
                const float hn = 1.0f - 2.0f / (e + 1.0f);
                hbuf[(t + 1) & 1][hidx(j)] = hn;
                hs[u] = hn;
            }
            LDS_BARRIER();
        }
        if (wr) {
#pragma unroll
            for (int u = 0; u < XPB; ++u)
                iob[(size_t)(t0 + u) * 256 + j] = hs[u];
            if (hfinal != nullptr && t0 == TT - XPB)
                hfinal[b * 256 + j] = hs[XPB - 1];
        }
        if (more) {
#pragma unroll
            for (int u = 0; u < XPB; ++u) xpc[u] = xpn[u];
        }
    }
}

__global__ __launch_bounds__(512)
__attribute__((amdgpu_waves_per_eu(2, 2))) void mega12_kernel(
    const float* __restrict__ W0, const float* __restrict__ W1,
    const float* __restrict__ b1v, const float* __restrict__ h0init,
    float* xpA, float* out, int* flags)
{
    __shared__ float lds[2][2 * HPAD];
    const int tid = threadIdx.x;
    const int p = tid & 3;
    const int q = tid >> 2;
    const int c = q & 1;
    const int j = (q >> 1) * 4 + p;
    const bool wr = (c == 0);
    const int bid = blockIdx.x;
    int* flagL0 = flags;               // stride 16 ints per batch (64B line)
    int* chunkdone = flags + BB * 16;  // stride NCHUNK ints per batch

    if (bid < BB || bid >= 3 * BB) {
        // ---- scan roles ----
        const bool isL0 = (bid < BB);
        const int b = isL0 ? bid : bid - 3 * BB;
        const float* W = isL0 ? W0 : W1;
        const float* h_init = isL0 ? h0init : (h0init + BB * 256);

        float w[128];
#pragma unroll
        for (int i = 0; i < 128; ++i)
            w[i] = W[(size_t)(256 + c * 128 + i) * 256 + j];

        if (tid < 256) lds[0][hidx(tid)] = h_init[b * 256 + tid];

        const float* xsrc = xpA + (size_t)b * TT * 256;
        float* hdst = out + (size_t)b * TT * 256;
        float xpc[XPB], xpn[XPB], hs[XPB];

        if (isL0) {
            if (wr) {
#pragma unroll
                for (int u = 0; u < XPB; ++u) xpc[u] = xsrc[(size_t)u * 256 + j];
            }
            __syncthreads();
            for (int t0 = 0; t0 < TT; t0 += XPB) {
                const bool more = (t0 + XPB) < TT;
                if (wr && more) {
#pragma unroll
                    for (int u = 0; u < XPB; ++u)
                        xpn[u] = xsrc[(size_t)(t0 + XPB + u) * 256 + j];
                }
#pragma unroll
                for (int u = 0; u < XPB; ++u) {
                    const int t = t0 + u;
                    const float* hb = &lds[t & 1][HPAD * c];
                    DOT128()
                    if (wr) {
                        const float z = s + xpc[u];
                        const float e = __expf(2.0f * z);
                        const float hn = 1.0f - 2.0f / (e + 1.0f);
                        lds[(t + 1) & 1][hidx(j)] = hn;
                        hs[u] = hn;
                    }
                    LDS_BARRIER();
                }
                if (wr) {
#pragma unroll
                    for (int u = 0; u < XPB; ++u)
                        hdst[(size_t)(t0 + u) * 256 + j] = hs[u];
                }
                if (((t0 + XPB) & (CHUNK - 1)) == 0) {
                    __threadfence();
                    __syncthreads();
                    if (tid == 0) astore(&flagL0[b * 16], t0 + XPB);
                }
                if (more) {
#pragma unroll
                    for (int u = 0; u < XPB; ++u) xpc[u] = xpn[u];
                }
            }
        } else {
            __syncthreads();
            for (int chunk = 0; chunk < NCHUNK; ++chunk) {
                const int tbase = chunk * CHUNK;
                while (rload(&chunkdone[b * NCHUNK + chunk]) == 0)
                    __builtin_amdgcn_s_sleep(1);
                __threadfence();  // single acquire (wb+inv) per chunk
                if (wr) {
#pragma unroll
                    for (int u = 0; u < XPB; ++u)
                        xpc[u] = xsrc[(size_t)(tbase + u) * 256 + j];
                }
                for (int g = 0; g < CHUNK / XPB; ++g) {
                    const int t0 = tbase + g * XPB;
                    if (wr && g + 1 < CHUNK / XPB) {
#pragma unroll
                        for (int u = 0; u < XPB; ++u)
                            xpn[u] = xsrc[(size_t)(t0 + XPB + u) * 256 + j];
                    }
#pragma unroll
                    for (int u = 0; u < XPB; ++u) {
                        const int t = t0 + u;
                        const float* hb = &lds[t & 1][HPAD * c];
                        DOT128()
                        if (wr) {
                            const float z = s + xpc[u];
                            const float e = __expf(2.0f * z);
                            const float hn = 1.0f - 2.0f / (e + 1.0f);
                            lds[(t + 1) & 1][hidx(j)] = hn;
                            hs[u] = hn;
                        }
                        LDS_BARRIER();
                    }
                    if (wr) {
#pragma unroll
                        for (int u = 0; u < XPB; ++u)
                            hdst[(size_t)(t0 + u) * 256 + j] = hs[u];
                        if (t0 + XPB == TT)
                            out[(size_t)BB * TT * 256 + b * 256 + j] = hs[XPB - 1];
                    }
                    if (g + 1 < CHUNK / XPB) {
#pragma unroll
                        for (int u = 0; u < XPB; ++u) xpc[u] = xpn[u];
                    }
                }
            }
        }
    } else {
        // ---- proj1 chasers (2 per batch) ----
        const int k = bid - BB;  // 0..63
        const int b = k >> 1;
        const int half = k & 1;

        float w[128];
#pragma unroll
        for (int i = 0; i < 128; ++i)
            w[i] = W1[(size_t)(c * 128 + i) * 256 + j];
        const float bj = b1v[j];

        for (int chunk = half; chunk < NCHUNK; chunk += 2) {
            while (rload(&flagL0[b * 16]) < (chunk + 1) * CHUNK)
                __builtin_amdgcn_s_sleep(1);
            __threadfence();  // single acquire (wb+inv) per chunk
            const int tbase = chunk * CHUNK;
            const float* src = out + ((size_t)b * TT + tbase) * 256;  // h0 rows
            float* dst = xpA + ((size_t)b * TT + tbase) * 256;        // xproj1

            if (tid < 64) {
                float4 t4 = reinterpret_cast<const float4*>(src)[tid];
                *reinterpret_cast<float4*>(&lds[0][hidx(4 * tid)]) = t4;
            }
            __syncthreads();
            for (int r = 0; r < CHUNK; ++r) {
                const int buf = r & 1;
                if (r + 1 < CHUNK && tid < 64) {
                    float4 t4 =
                        reinterpret_cast<const float4*>(src + (size_t)(r + 1) * 256)[tid];
                    *reinterpret_cast<float4*>(&lds[buf ^ 1][hidx(4 * tid)]) = t4;
                }
                const float* hb = &lds[buf][HPAD * c];
                DOT128()
                if (wr) dst[(size_t)r * 256 + j] = s + bj;
                __syncthreads();
            }
            __threadfence();
            __syncthreads();
            if (tid == 0) astore(&chunkdone[b * NCHUNK + chunk], 1);
        }
    }
}

extern "C" void kernel_launch(void* const* d_in, const int* in_sizes, int n_in,
                              void* d_out, int out_size, void* d_ws, size_t ws_size,
                              hipStream_t stream) {
    const float* x  = (const float*)d_in[0];  // [B,T,256]
    const float* h0 = (const float*)d_in[1];  // [2,B,256]
    const float* W0 = (const float*)d_in[2];  // [512,256]
    const float* b0 = (const float*)d_in[3];  // [256]
    const float* W1 = (const float*)d_in[4];  // [512,256]
    const float* b1 = (const float*)d_in[5];  // [256]
    float* out = (float*)d_out;               // [B*T*256] + [B*256]

    const size_t XPA_FLOATS = (size_t)BB * TT * 256;  // 64 MB
    const size_t FLAG_INTS = (size_t)BB * 16 + (size_t)BB * NCHUNK;
    const size_t NEEDED = XPA_FLOATS * 4 + FLAG_INTS * 4;

    if (ws_size >= NEEDED) {
        float* xpA = (float*)d_ws;
        int* flags = (int*)((char*)d_ws + XPA_FLOATS * 4);
        hipMemsetAsync(flags, 0, FLAG_INTS * 4, stream);
        proj12_kernel<<<256, 512, 0, stream>>>(x, W0, b0, xpA, 256);
        mega12_kernel<<<4 * BB, 512, 0, stream>>>(W0, W1, b1, h0, xpA, out, flags);
    } else {
        proj12_kernel<<<256, 512, 0, stream>>>(x, W0, b0, out, 256);
        scan12_kernel<<<BB, 512, 0, stream>>>(W0, h0, out, nullptr);
        proj12_kernel<<<256, 512, 0, stream>>>(out, W1, b1, out, 256);
        scan12_kernel<<<BB, 512, 0, stream>>>(W1, h0 + BB * 256, out, out + XPA_FLOATS);
    }
}

// Round 13
// 2250.389 us; speedup vs baseline: 1.5593x; 1.1894x over previous
//
#include <hip/hip_runtime.h>

// RNN: B=32, T=2048, E=256, H=256, L=2, f32.
// Pipelined megakernel (r8-proven structure + minimal sync + VGPR keep-alive):
//   pre: proj0 = x @ W0x + b0 -> ws.A  (grid 256)
//   mega (128 blocks, all co-resident):
//     blk 0-31   L0 scan -> d_out rows; publish flagL0[b] every CHUNK steps
//     blk 32-95  chasers (2/batch): xproj1 = h0 @ W1x + b1 -> ws.A
//     blk 96-127 L1 scan: wait chunkdone -> d_out rows + ht
//
// SYNC (r13): publisher = __syncthreads() (vmcnt drain) + ONE release astore
// (emits its own wbl2) — r12's extra __threadfence doubled the wb cost and
// CHUNK=32 doubled the count; both reverted. Consumer = RELAXED poll + ONE
// acquire fence (inv only) per chunk.
//
// KEEP-ALIVE (r13, parking fight #8): a volatile empty asm per step lists all
// 128 weights as "+v" tied operands. Every weight must be in an ARCH VGPR at
// that point each iteration, so AGPR-parking now costs 128 reads + 128 writes
// per step vs 0 for staying resident (128+~60 misc < 256 budget at 2 w/EU) —
// residency becomes the allocator's cheapest plan. Rounds 4-10 failed because
// per-use single "v" reads looked cheap; the tied-operand round-trip doesn't.
//
// Dot core (r4/r6/r8-proven): 512 thr, p=tid&3, q=tid>>2, c=q&1, j=(q>>1)*4+p;
// ds_read_b128 (HPAD=144, conflict-free) + per-FMA v_fmac_f32_dpp (quad_perm
// broadcast folded), shfl_xor(4) reduce. Scan barriers: LDS-only
// "s_waitcnt lgkmcnt(0); s_barrier"; global I/O in XPB=8 groups.

#define TT 2048
#define BB 32
#define XPB 8
#define HPAD 144  // padded stride of one 128-float h half
#define CHUNK 64
#define NCHUNK (TT / CHUNK)  // 32

#define FMAC1(acc, hv, wv, QPS)                                               \
    asm("v_fmac_f32_dpp %0, %1, %2 quad_perm:[" QPS "] row_mask:0xf "         \
        "bank_mask:0xf"                                                       \
        : "+v"(acc)                                                           \
        : "v"(hv), "v"(wv))

#define QBLK(S, QPS)                          \
    FMAC1(a0, v.x, w[base + 4 * S + 0], QPS); \
    FMAC1(a1, v.y, w[base + 4 * S + 1], QPS); \
    FMAC1(a2, v.z, w[base + 4 * S + 2], QPS); \
    FMAC1(a3, v.w, w[base + 4 * S + 3], QPS);

// keep-alive: force all 128 weights into arch VGPRs once per step
#define KL8(W, B)                                                      \
    "+v"((W)[(B)]), "+v"((W)[(B) + 1]), "+v"((W)[(B) + 2]),            \
    "+v"((W)[(B) + 3]), "+v"((W)[(B) + 4]), "+v"((W)[(B) + 5]),        \
    "+v"((W)[(B) + 6]), "+v"((W)[(B) + 7])
#define KEEPALIVE(W)                                                   \
    asm volatile("" : KL8(W, 0), KL8(W, 8), KL8(W, 16), KL8(W, 24));   \
    asm volatile("" : KL8(W, 32), KL8(W, 40), KL8(W, 48), KL8(W, 56)); \
    asm volatile("" : KL8(W, 64), KL8(W, 72), KL8(W, 80), KL8(W, 88)); \
    asm volatile("" : KL8(W, 96), KL8(W, 104), KL8(W, 112), KL8(W, 120));

#define DOT128()                                                        \
    KEEPALIVE(w)                                                        \
    float a0 = 0.f, a1 = 0.f, a2 = 0.f, a3 = 0.f;                       \
    _Pragma("unroll")                                                   \
    for (int k = 0; k < 8; ++k) {                                       \
        const int base = 16 * k;                                        \
        float4 v = *reinterpret_cast<const float4*>(hb + base + 4 * p); \
        QBLK(0, "0,0,0,0")                                              \
        QBLK(1, "1,1,1,1")                                              \
        QBLK(2, "2,2,2,2")                                              \
        QBLK(3, "3,3,3,3")                                              \
    }                                                                   \
    float s = (a0 + a1) + (a2 + a3);                                    \
    s += __shfl_xor(s, 4, 64);

#define LDS_BARRIER() asm volatile("s_waitcnt lgkmcnt(0)\n\ts_barrier" ::: "memory")

__device__ __forceinline__ int hidx(int i) { return HPAD * (i >> 7) + (i & 127); }

__device__ __forceinline__ int rload(int* pf) {
    return __hip_atomic_load(pf, __ATOMIC_RELAXED, __HIP_MEMORY_SCOPE_AGENT);
}
__device__ __forceinline__ void astore(int* pf, int v) {
    __hip_atomic_store(pf, v, __ATOMIC_RELEASE, __HIP_MEMORY_SCOPE_AGENT);
}
#define ACQUIRE_FENCE() __builtin_amdgcn_fence(__ATOMIC_ACQUIRE, "agent")

__global__ __launch_bounds__(512)
__attribute__((amdgpu_waves_per_eu(2, 2))) void proj13_kernel(
    const float* in, const float* __restrict__ W, const float* __restrict__ bias,
    float* out, int rows_per_wg)
{
    __shared__ float rb[2][2 * HPAD];
    const int tid = threadIdx.x;
    const int p = tid & 3;
    const int q = tid >> 2;
    const int c = q & 1;
    const int j = (q >> 1) * 4 + p;

    float w[128];
#pragma unroll
    for (int i = 0; i < 128; ++i)
        w[i] = W[(size_t)(c * 128 + i) * 256 + j];
    const float bj = bias[j];

    const size_t r0 = (size_t)blockIdx.x * rows_per_wg;
    if (tid < 64) {
        float4 t4 = reinterpret_cast<const float4*>(in + r0 * 256)[tid];
        *reinterpret_cast<float4*>(&rb[0][hidx(4 * tid)]) = t4;
    }
    __syncthreads();

    for (int rr = 0; rr < rows_per_wg; ++rr) {
        const int buf = rr & 1;
        if (rr + 1 < rows_per_wg && tid < 64) {
            float4 t4 = reinterpret_cast<const float4*>(in + (r0 + rr + 1) * 256)[tid];
            *reinterpret_cast<float4*>(&rb[buf ^ 1][hidx(4 * tid)]) = t4;
        }
        const float* hb = &rb[buf][HPAD * c];
        DOT128()
        if (c == 0) out[(r0 + rr) * 256 + j] = s + bj;
        __syncthreads();
    }
}

// serial fallback scan
__global__ __launch_bounds__(512)
__attribute__((amdgpu_waves_per_eu(2, 2))) void scan13_kernel(
    const float* __restrict__ W, const float* __restrict__ h_init,
    float* __restrict__ io, float* __restrict__ hfinal)
{
    __shared__ float hbuf[2][2 * HPAD];
    const int tid = threadIdx.x;
    const int p = tid & 3;
    const int q = tid >> 2;
    const int c = q & 1;
    const int j = (q >> 1) * 4 + p;
    const int b = blockIdx.x;
    const bool wr = (c == 0);

    float w[128];
#pragma unroll
    for (int i = 0; i < 128; ++i)
        w[i] = W[(size_t)(256 + c * 128 + i) * 256 + j];

    if (tid < 256) hbuf[0][hidx(tid)] = h_init[b * 256 + tid];

    float* iob = io + (size_t)b * TT * 256;
    float xpc[XPB], xpn[XPB], hs[XPB];
    if (wr) {
#pragma unroll
        for (int u = 0; u < XPB; ++u) xpc[u] = iob[(size_t)u * 256 + j];
    }
    __syncthreads();

    for (int t0 = 0; t0 < TT; t0 += XPB) {
        const bool more = (t0 + XPB) < TT;
        if (wr && more) {
#pragma unroll
            for (int u = 0; u < XPB; ++u)
                xpn[u] = iob[(size_t)(t0 + XPB + u) * 256 + j];
        }
#pragma unroll
        for (int u = 0; u < XPB; ++u) {
            const int t = t0 + u;
            const float* hb = &hbuf[t & 1][HPAD * c];
            DOT128()
            if (wr) {
                const float z = s + xpc[u];
                const float e = __expf(2.0f * z);
                const float hn = 1.0f - 2.0f / (e + 1.0f);
                hbuf[(t + 1) & 1][hidx(j)] = hn;
                hs[u] = hn;
            }
            LDS_BARRIER();
        }
        if (wr) {
#pragma unroll
            for (int u = 0; u < XPB; ++u)
                iob[(size_t)(t0 + u) * 256 + j] = hs[u];
            if (hfinal != nullptr && t0 == TT - XPB)
                hfinal[b * 256 + j] = hs[XPB - 1];
        }
        if (more) {
#pragma unroll
            for (int u = 0; u < XPB; ++u) xpc[u] = xpn[u];
        }
    }
}

__global__ __launch_bounds__(512)
__attribute__((amdgpu_waves_per_eu(2, 2))) void mega13_kernel(
    const float* __restrict__ W0, const float* __restrict__ W1,
    const float* __restrict__ b1v, const float* __restrict__ h0init,
    float* xpA, float* out, int* flags)
{
    __shared__ float lds[2][2 * HPAD];
    const int tid = threadIdx.x;
    const int p = tid & 3;
    const int q = tid >> 2;
    const int c = q & 1;
    const int j = (q >> 1) * 4 + p;
    const bool wr = (c == 0);
    const int bid = blockIdx.x;
    int* flagL0 = flags;               // stride 16 ints per batch (64B line)
    int* chunkdone = flags + BB * 16;  // stride NCHUNK(=32) ints per batch

    if (bid < BB || bid >= 3 * BB) {
        // ---- scan roles ----
        const bool isL0 = (bid < BB);
        const int b = isL0 ? bid : bid - 3 * BB;
        const float* W = isL0 ? W0 : W1;
        const float* h_init = isL0 ? h0init : (h0init + BB * 256);

        float w[128];
#pragma unroll
        for (int i = 0; i < 128; ++i)
            w[i] = W[(size_t)(256 + c * 128 + i) * 256 + j];

        if (tid < 256) lds[0][hidx(tid)] = h_init[b * 256 + tid];

        const float* xsrc = xpA + (size_t)b * TT * 256;
        float* hdst = out + (size_t)b * TT * 256;
        float xpc[XPB], xpn[XPB], hs[XPB];

        if (isL0) {
            if (wr) {
#pragma unroll
                for (int u = 0; u < XPB; ++u) xpc[u] = xsrc[(size_t)u * 256 + j];
            }
            __syncthreads();
            for (int t0 = 0; t0 < TT; t0 += XPB) {
                const bool more = (t0 + XPB) < TT;
                if (wr && more) {
#pragma unroll
                    for (int u = 0; u < XPB; ++u)
                        xpn[u] = xsrc[(size_t)(t0 + XPB + u) * 256 + j];
                }
#pragma unroll
                for (int u = 0; u < XPB; ++u) {
                    const int t = t0 + u;
                    const float* hb = &lds[t & 1][HPAD * c];
                    DOT128()
                    if (wr) {
                        const float z = s + xpc[u];
                        const float e = __expf(2.0f * z);
                        const float hn = 1.0f - 2.0f / (e + 1.0f);
                        lds[(t + 1) & 1][hidx(j)] = hn;
                        hs[u] = hn;
                    }
                    LDS_BARRIER();
                }
                if (wr) {
#pragma unroll
                    for (int u = 0; u < XPB; ++u)
                        hdst[(size_t)(t0 + u) * 256 + j] = hs[u];
                }
                if (((t0 + XPB) & (CHUNK - 1)) == 0) {
                    // __syncthreads drains all waves' vmcnt; release store
                    // does its own wbl2 before the flag write.
                    __syncthreads();
                    if (tid == 0) astore(&flagL0[b * 16], t0 + XPB);
                }
                if (more) {
#pragma unroll
                    for (int u = 0; u < XPB; ++u) xpc[u] = xpn[u];
                }
            }
        } else {
            __syncthreads();
            for (int chunk = 0; chunk < NCHUNK; ++chunk) {
                const int tbase = chunk * CHUNK;
                while (rload(&chunkdone[b * NCHUNK + chunk]) == 0)
                    __builtin_amdgcn_s_sleep(1);
                ACQUIRE_FENCE();  // one inv per chunk
                if (wr) {
#pragma unroll
                    for (int u = 0; u < XPB; ++u)
                        xpc[u] = xsrc[(size_t)(tbase + u) * 256 + j];
                }
                for (int g = 0; g < CHUNK / XPB; ++g) {
                    const int t0 = tbase + g * XPB;
                    if (wr && g + 1 < CHUNK / XPB) {
#pragma unroll
                        for (int u = 0; u < XPB; ++u)
                            xpn[u] = xsrc[(size_t)(t0 + XPB + u) * 256 + j];
                    }
#pragma unroll
                    for (int u = 0; u < XPB; ++u) {
                        const int t = t0 + u;
                        const float* hb = &lds[t & 1][HPAD * c];
                        DOT128()
                        if (wr) {
                            const float z = s + xpc[u];
                            const float e = __expf(2.0f * z);
                            const float hn = 1.0f - 2.0f / (e + 1.0f);
                            lds[(t + 1) & 1][hidx(j)] = hn;
                            hs[u] = hn;
                        }
                        LDS_BARRIER();
                    }
                    if (wr) {
#pragma unroll
                        for (int u = 0; u < XPB; ++u)
                            hdst[(size_t)(t0 + u) * 256 + j] = hs[u];
                        if (t0 + XPB == TT)
                            out[(size_t)BB * TT * 256 + b * 256 + j] = hs[XPB - 1];
                    }
                    if (g + 1 < CHUNK / XPB) {
#pragma unroll
                        for (int u = 0; u < XPB; ++u) xpc[u] = xpn[u];
                    }
                }
            }
        }
    } else {
        // ---- proj1 chasers (2 per batch) ----
        const int k = bid - BB;  // 0..63
        const int b = k >> 1;
        const int half = k & 1;

        float w[128];
#pragma unroll
        for (int i = 0; i < 128; ++i)
            w[i] = W1[(size_t)(c * 128 + i) * 256 + j];
        const float bj = b1v[j];

        for (int chunk = half; chunk < NCHUNK; chunk += 2) {
            while (rload(&flagL0[b * 16]) < (chunk + 1) * CHUNK)
                __builtin_amdgcn_s_sleep(1);
            ACQUIRE_FENCE();  // one inv per chunk
            const int tbase = chunk * CHUNK;
            const float* src = out + ((size_t)b * TT + tbase) * 256;  // h0 rows
            float* dst = xpA + ((size_t)b * TT + tbase) * 256;        // xproj1

            if (tid < 64) {
                float4 t4 = reinterpret_cast<const float4*>(src)[tid];
                *reinterpret_cast<float4*>(&lds[0][hidx(4 * tid)]) = t4;
            }
            __syncthreads();
            for (int r = 0; r < CHUNK; ++r) {
                const int buf = r & 1;
                if (r + 1 < CHUNK && tid < 64) {
                    float4 t4 =
                        reinterpret_cast<const float4*>(src + (size_t)(r + 1) * 256)[tid];
                    *reinterpret_cast<float4*>(&lds[buf ^ 1][hidx(4 * tid)]) = t4;
                }
                const float* hb = &lds[buf][HPAD * c];
                DOT128()
                if (wr) dst[(size_t)r * 256 + j] = s + bj;
                __syncthreads();
            }
            __syncthreads();
            if (tid == 0) astore(&chunkdone[b * NCHUNK + chunk], 1);
        }
    }
}

extern "C" void kernel_launch(void* const* d_in, const int* in_sizes, int n_in,
                              void* d_out, int out_size, void* d_ws, size_t ws_size,
                              hipStream_t stream) {
    const float* x  = (const float*)d_in[0];  // [B,T,256]
    const float* h0 = (const float*)d_in[1];  // [2,B,256]
    const float* W0 = (const float*)d_in[2];  // [512,256]
    const float* b0 = (const float*)d_in[3];  // [256]
    const float* W1 = (const float*)d_in[4];  // [512,256]
    const float* b1 = (const float*)d_in[5];  // [256]
    float* out = (float*)d_out;               // [B*T*256] + [B*256]

    const size_t XPA_FLOATS = (size_t)BB * TT * 256;  // 64 MB
    const size_t FLAG_INTS = (size_t)BB * 16 + (size_t)BB * NCHUNK;
    const size_t NEEDED = XPA_FLOATS * 4 + FLAG_INTS * 4;

    if (ws_size >= NEEDED) {
        float* xpA = (float*)d_ws;
        int* flags = (int*)((char*)d_ws + XPA_FLOATS * 4);
        hipMemsetAsync(flags, 0, FLAG_INTS * 4, stream);
        proj13_kernel<<<256, 512, 0, stream>>>(x, W0, b0, xpA, 256);
        mega13_kernel<<<4 * BB, 512, 0, stream>>>(W0, W1, b1, h0, xpA, out, flags);
    } else {
        proj13_kernel<<<256, 512, 0, stream>>>(x, W0, b0, out, 256);
        scan13_kernel<<<BB, 512, 0, stream>>>(W0, h0, out, nullptr);
        proj13_kernel<<<256, 512, 0, stream>>>(out, W1, b1, out, 256);
        scan13_kernel<<<BB, 512, 0, stream>>>(W1, h0 + BB * 256, out, out + XPA_FLOATS);
    }
}